// Round 5
// baseline (144.495 us; speedup 1.0000x reference)
//
#include <hip/hip_runtime.h>
#include <hip/hip_bf16.h>

#define B_ 128
#define T_ 256
#define D_ 1024
#define L_ 48
#define SMALL_ (-1000.0f)

typedef float f32x4 __attribute__((ext_vector_type(4)));
typedef short bf16x8 __attribute__((ext_vector_type(8)));
typedef unsigned u32x4 __attribute__((ext_vector_type(4)));

__device__ __forceinline__ float bcastf(float v, int lane) {
    return __uint_as_float(__builtin_amdgcn_readlane(__float_as_uint(v), lane));
}
__device__ __forceinline__ unsigned cvt_pk_bf16(float lo, float hi) {
    unsigned r;
    asm("v_cvt_pk_bf16_f32 %0, %1, %2" : "=v"(r) : "v"(lo), "v"(hi));
    return r;
}

// ---------- Kernel 1: W f32 -> bf16, + zero the reduction ticket ----------
__global__ __launch_bounds__(256) void wconv_kernel(const float* __restrict__ W,
                                                    unsigned short* __restrict__ wbf,
                                                    unsigned* __restrict__ cnt) {
    int i = blockIdx.x * 256 + threadIdx.x;  // 48*1024 = 49152
    if (i == 0) *cnt = 0u;
    unsigned u = __float_as_uint(W[i]);
    wbf[i] = (unsigned short)((u + 0x7FFFu + ((u >> 16) & 1u)) >> 16);
}

// ---------- Kernel 2: fused per-batch GEMM (-> LDS) + CRF forward + gold + reduce ----------
__global__ __launch_bounds__(256) void mega_kernel(const float* __restrict__ x,
                                                   const unsigned short* __restrict__ wbf,
                                                   const float* __restrict__ bias,
                                                   const float* __restrict__ trans,
                                                   const int* __restrict__ tags,
                                                   const int* __restrict__ seq_len,
                                                   float* __restrict__ res,
                                                   unsigned* __restrict__ cnt,
                                                   float* __restrict__ out) {
    __shared__ float elds[T_ * L_];   // 48 KB: this batch's pred
    __shared__ float s_sc;
    const int b = blockIdx.x;
    const int tid = threadIdx.x;
    const int wv = tid >> 6;
    const int j = tid & 63;
    const int n = seq_len[b];         // 1..256

    // ---- phase 1: pred[b] = x[b] @ W^T + bias  -> LDS ----
    {
        const int l16 = j & 15;
        const int lg  = j >> 4;       // k-group 0..3
        float bi0 = bias[l16], bi1 = bias[16 + l16], bi2 = bias[32 + l16];
        const unsigned short* wrow = wbf + (size_t)l16 * D_ + lg * 8;

        #pragma unroll
        for (int tile = 0; tile < 4; ++tile) {     // wave wv owns M-tiles wv*4+tile
            const int trow = (wv * 4 + tile) * 16; // t offset of this 16-row tile
            const float* xrow = x + ((size_t)b * T_ + trow + l16) * D_ + lg * 8;
            f32x4 acc0 = {0.f,0.f,0.f,0.f}, acc1 = {0.f,0.f,0.f,0.f}, acc2 = {0.f,0.f,0.f,0.f};

            #pragma unroll 4
            for (int k0 = 0; k0 < D_; k0 += 32) {
                float4 xa = *reinterpret_cast<const float4*>(xrow + k0);
                float4 xb = *reinterpret_cast<const float4*>(xrow + k0 + 4);
                u32x4 au;
                au[0] = cvt_pk_bf16(xa.x, xa.y);
                au[1] = cvt_pk_bf16(xa.z, xa.w);
                au[2] = cvt_pk_bf16(xb.x, xb.y);
                au[3] = cvt_pk_bf16(xb.z, xb.w);
                bf16x8 af = __builtin_bit_cast(bf16x8, au);
                const unsigned short* wp = wrow + k0;
                bf16x8 b0 = *reinterpret_cast<const bf16x8*>(wp);
                bf16x8 b1 = *reinterpret_cast<const bf16x8*>(wp + 16 * D_);
                bf16x8 b2 = *reinterpret_cast<const bf16x8*>(wp + 32 * D_);
                acc0 = __builtin_amdgcn_mfma_f32_16x16x32_bf16(af, b0, acc0, 0, 0, 0);
                acc1 = __builtin_amdgcn_mfma_f32_16x16x32_bf16(af, b1, acc1, 0, 0, 0);
                acc2 = __builtin_amdgcn_mfma_f32_16x16x32_bf16(af, b2, acc2, 0, 0, 0);
            }
            // C layout: col = lane&15, row = (lane>>4)*4 + reg
            #pragma unroll
            for (int r = 0; r < 4; ++r) {
                int row = trow + lg * 4 + r;
                elds[row * L_ + l16]      = acc0[r] + bi0;
                elds[row * L_ + 16 + l16] = acc1[r] + bi1;
                elds[row * L_ + 32 + l16] = acc2[r] + bi2;
            }
        }
    }
    __syncthreads();

    if (wv == 1) {
        // ---- gold-path score (reads LDS pred) ----
        const int* tg = tags + b * T_;
        float sc = 0.f;
        for (int t = j; t < n; t += 64) {
            int tag = tg[t];
            int pt = (t == 0) ? (L_ - 2) : tg[t - 1];
            sc += elds[t * L_ + tag] + trans[pt * L_ + tag];
        }
        if (j == 0) sc += trans[tg[n - 1] * L_ + (L_ - 1)];
        #pragma unroll
        for (int o = 32; o > 0; o >>= 1) sc += __shfl_xor(sc, o, 64);
        if (j == 0) s_sc = sc;
    }

    float logz = 0.f;
    if (wv == 0) {
        // E column (f32): E[i] = exp(trans[i][jj])
        float E[48];
        {
            const int jj = (j < L_) ? j : (L_ - 1);
            #pragma unroll
            for (int i = 0; i < 48; ++i) E[i] = __expf(trans[i * L_ + jj]);
        }

        // ---- forward recursion, f32 linear space, renorm every 8 (R4-proven) ----
        const bool em = (j < L_ - 2);
        const int jsafe = em ? j : 0;
        float a = (j == (L_ - 2)) ? 1.f : 0.f;   // exp(alpha) normalized
        float M = 0.f;                            // running log-offset
        float xe = __expf(em ? elds[j] : SMALL_);            // emission exp, step 1
        float nx = (em && n > 1) ? elds[L_ + j] : SMALL_;    // raw emission, step 2

        for (int s = 1; s <= n; ++s) {
            int pfrow = (s + 1 < n) ? (s + 1) : 0;
            float ldn = elds[pfrow * L_ + jsafe];            // prefetch step s+2

            float a0 = 0.f, a1 = 0.f, a2 = 0.f, a3 = 0.f;
            #pragma unroll
            for (int i = 0; i < 48; i += 4) {
                a0 = fmaf(bcastf(a, i + 0), E[i + 0], a0);
                a1 = fmaf(bcastf(a, i + 1), E[i + 1], a1);
                a2 = fmaf(bcastf(a, i + 2), E[i + 2], a2);
                a3 = fmaf(bcastf(a, i + 3), E[i + 3], a3);
            }
            float raw = (a0 + a1) + (a2 + a3);   // strictly positive
            if ((s & 7) == 0) {                  // periodic renormalization
                float r = bcastf(raw, 0);
                raw *= __builtin_amdgcn_rcpf(r);
                M += __logf(r);
            }
            a = raw * xe;
            xe = __expf(nx);
            nx = (em && s + 1 < n) ? ldn : SMALL_;
        }

        // final transition-to-end: only lane L-1's value matters
        float a0 = 0.f, a1 = 0.f, a2 = 0.f, a3 = 0.f;
        #pragma unroll
        for (int i = 0; i < 48; i += 4) {
            a0 = fmaf(bcastf(a, i + 0), E[i + 0], a0);
            a1 = fmaf(bcastf(a, i + 1), E[i + 1], a1);
            a2 = fmaf(bcastf(a, i + 2), E[i + 2], a2);
            a3 = fmaf(bcastf(a, i + 3), E[i + 3], a3);
        }
        float raw_end = (a0 + a1) + (a2 + a3);
        float vz = bcastf(raw_end, L_ - 1);
        logz = __logf(vz) + M;
    }
    __syncthreads();

    if (wv == 0) {
        if (j == 0) res[b] = logz - s_sc;
        // fused deterministic reduce: last block sums all 128 in fixed order
        __threadfence();
        unsigned old = 0;
        if (j == 0) old = atomicAdd(cnt, 1u);
        old = __builtin_amdgcn_readlane(old, 0);
        if (old == B_ - 1) {
            __threadfence();
            volatile const float* vr = res;
            float v2 = vr[j] + vr[64 + j];
            #pragma unroll
            for (int o = 32; o > 0; o >>= 1) v2 += __shfl_xor(v2, o, 64);
            if (j == 0) out[0] = v2;
        }
    }
}

extern "C" void kernel_launch(void* const* d_in, const int* in_sizes, int n_in,
                              void* d_out, int out_size, void* d_ws, size_t ws_size,
                              hipStream_t stream) {
    const float* x      = (const float*)d_in[0];
    const float* W      = (const float*)d_in[1];
    const float* bias   = (const float*)d_in[2];
    const float* trans  = (const float*)d_in[3];
    const int*   tags   = (const int*)d_in[4];
    const int*   seqlen = (const int*)d_in[5];
    float* out = (float*)d_out;

    unsigned short* wbf = (unsigned short*)d_ws;                 // 98304 B
    float* res = (float*)((char*)d_ws + 98304);                  // 512 B
    unsigned* cnt = (unsigned*)((char*)d_ws + 98816);            // 4 B

    hipLaunchKernelGGL(wconv_kernel, dim3(192), dim3(256), 0, stream, W, wbf, cnt);
    hipLaunchKernelGGL(mega_kernel, dim3(B_), dim3(256), 0, stream,
                       x, wbf, bias, trans, tags, seqlen, res, cnt, out);
}

// Round 6
// 122.038 us; speedup vs baseline: 1.1840x; 1.1840x over previous
//
#include <hip/hip_runtime.h>
#include <hip/hip_bf16.h>

#define B_ 128
#define T_ 256
#define D_ 1024
#define L_ 48
#define SMALL_ (-1000.0f)

typedef float f32x4 __attribute__((ext_vector_type(4)));
typedef short bf16x8 __attribute__((ext_vector_type(8)));
typedef unsigned u32x4 __attribute__((ext_vector_type(4)));

__device__ __forceinline__ float bcastf(float v, int lane) {
    return __uint_as_float(__builtin_amdgcn_readlane(__float_as_uint(v), lane));
}
__device__ __forceinline__ unsigned cvt_pk_bf16(float lo, float hi) {
    unsigned r;
    asm("v_cvt_pk_bf16_f32 %0, %1, %2" : "=v"(r) : "v"(lo), "v"(hi));
    return r;
}

// ---------- Kernel 1: W f32 -> bf16, + zero the reduction ticket ----------
__global__ __launch_bounds__(256) void wconv_kernel(const float* __restrict__ W,
                                                    unsigned short* __restrict__ wbf,
                                                    unsigned* __restrict__ cnt) {
    int i = blockIdx.x * 256 + threadIdx.x;  // 48*1024 = 49152
    if (i == 0) *cnt = 0u;
    unsigned u = __float_as_uint(W[i]);
    wbf[i] = (unsigned short)((u + 0x7FFFu + ((u >> 16) & 1u)) >> 16);
}

// ---------- Kernel 2: pred = x @ W^T + b, bf16 MFMA, 2-way K-split (R4-proven) ----------
__global__ __launch_bounds__(256, 4) void gemm_kernel(const float* __restrict__ x,
                                                      const unsigned short* __restrict__ wbf,
                                                      const float* __restrict__ bias,
                                                      float* __restrict__ pred) {
    __shared__ float red[2][64][12];
    const int wv = threadIdx.x >> 6;
    const int lane = threadIdx.x & 63;
    const int pair = wv >> 1;        // which 16-row tile
    const int kh = wv & 1;           // which K half
    const int m0 = blockIdx.x * 32 + pair * 16;   // grid 1024 -> 32768 rows
    const int l16 = lane & 15;
    const int lg  = lane >> 4;

    const float* xrow = x + (size_t)(m0 + l16) * D_ + kh * 512 + lg * 8;
    const unsigned short* wrow = wbf + (size_t)l16 * D_ + kh * 512 + lg * 8;
    f32x4 acc0 = {0.f,0.f,0.f,0.f}, acc1 = {0.f,0.f,0.f,0.f}, acc2 = {0.f,0.f,0.f,0.f};

    #pragma unroll 8
    for (int k0 = 0; k0 < 512; k0 += 32) {
        float4 xa = *reinterpret_cast<const float4*>(xrow + k0);
        float4 xb = *reinterpret_cast<const float4*>(xrow + k0 + 4);
        u32x4 au;
        au[0] = cvt_pk_bf16(xa.x, xa.y);
        au[1] = cvt_pk_bf16(xa.z, xa.w);
        au[2] = cvt_pk_bf16(xb.x, xb.y);
        au[3] = cvt_pk_bf16(xb.z, xb.w);
        bf16x8 af = __builtin_bit_cast(bf16x8, au);
        const unsigned short* wp = wrow + k0;
        bf16x8 b0 = *reinterpret_cast<const bf16x8*>(wp);
        bf16x8 b1 = *reinterpret_cast<const bf16x8*>(wp + 16 * D_);
        bf16x8 b2 = *reinterpret_cast<const bf16x8*>(wp + 32 * D_);
        acc0 = __builtin_amdgcn_mfma_f32_16x16x32_bf16(af, b0, acc0, 0, 0, 0);
        acc1 = __builtin_amdgcn_mfma_f32_16x16x32_bf16(af, b1, acc1, 0, 0, 0);
        acc2 = __builtin_amdgcn_mfma_f32_16x16x32_bf16(af, b2, acc2, 0, 0, 0);
    }

    if (kh == 1) {
        #pragma unroll
        for (int r = 0; r < 4; ++r) {
            red[pair][lane][r]     = acc0[r];
            red[pair][lane][4 + r] = acc1[r];
            red[pair][lane][8 + r] = acc2[r];
        }
    }
    __syncthreads();
    if (kh == 0) {
        const int rbase = m0 + lg * 4;
        float bi0 = bias[l16], bi1 = bias[16 + l16], bi2 = bias[32 + l16];
        #pragma unroll
        for (int r = 0; r < 4; ++r) {
            size_t ro = (size_t)(rbase + r) * L_;
            pred[ro + l16]      = acc0[r] + red[pair][lane][r]     + bi0;
            pred[ro + 16 + l16] = acc1[r] + red[pair][lane][4 + r] + bi1;
            pred[ro + 32 + l16] = acc2[r] + red[pair][lane][8 + r] + bi2;
        }
    }
}

// ---------- Kernel 3: CRF forward — LDS-broadcast inner loop (no readlane/SGPR hazards) ----------
__global__ __launch_bounds__(256) void crf_kernel(const float* __restrict__ pred,
                                                  const float* __restrict__ trans,
                                                  const int* __restrict__ tags,
                                                  const int* __restrict__ seq_len,
                                                  float* __restrict__ res,
                                                  unsigned* __restrict__ cnt,
                                                  float* __restrict__ out) {
    __shared__ float elds[T_ * L_];   // 48 KB: pred[b] staged
    __shared__ float abuf[2][64];     // double-buffered alpha broadcast slot
    __shared__ float s_sc;
    const int b = blockIdx.x;
    const int tid = threadIdx.x;
    const int wv = tid >> 6;
    const int j = tid & 63;
    const int n = seq_len[b];         // 1..256
    const float* pb = pred + (size_t)b * T_ * L_;

    // E column (f32): E[i] = exp(trans[i][jj]) — global loads, no LDS dep
    float E[48];
    if (wv == 0) {
        const int jj = (j < L_) ? j : (L_ - 1);
        #pragma unroll
        for (int i = 0; i < 48; ++i) E[i] = __expf(trans[i * L_ + jj]);
    }

    // stage pred[b] -> LDS (all 4 waves, float4)
    #pragma unroll
    for (int i = 0; i < 12; ++i) {
        int idx = tid + i * 256;                       // float4 index, 3072 total
        float4 v = *reinterpret_cast<const float4*>(pb + (size_t)idx * 4);
        *reinterpret_cast<float4*>(elds + idx * 4) = v;
    }
    __syncthreads();

    if (wv == 1) {
        // ---- gold-path score (reads staged LDS) ----
        const int* tg = tags + b * T_;
        float sc = 0.f;
        for (int t = j; t < n; t += 64) {
            int tag = tg[t];
            int pt = (t == 0) ? (L_ - 2) : tg[t - 1];
            sc += elds[t * L_ + tag] + trans[pt * L_ + tag];
        }
        if (j == 0) sc += trans[tg[n - 1] * L_ + (L_ - 1)];
        #pragma unroll
        for (int o = 32; o > 0; o >>= 1) sc += __shfl_xor(sc, o, 64);
        if (j == 0) s_sc = sc;
    }

    float logz = 0.f;
    if (wv == 0) {
        // ---- forward recursion, f32 linear space; alpha broadcast via LDS ----
        const bool em = (j < L_ - 2);
        const int jsafe = em ? j : 0;
        float M = 0.f;                                       // running log-offset
        float xe = __expf(em ? elds[j] : SMALL_);            // emission exp, step 1
        float nx = (em && n > 1) ? elds[L_ + j] : SMALL_;    // raw emission, step 2

        abuf[1][j] = (j == (L_ - 2)) ? 1.f : 0.f;            // init alpha for step 1

        for (int s = 1; s <= n; ++s) {
            int pfrow = (s + 1 < n) ? (s + 1) : 0;
            float ldn = elds[pfrow * L_ + jsafe];            // prefetch step s+2

            const float4* a4 = reinterpret_cast<const float4*>(abuf[s & 1]);
            float a0 = 0.f, a1 = 0.f, a2 = 0.f, a3 = 0.f;
            #pragma unroll
            for (int c = 0; c < 12; ++c) {
                float4 va = a4[c];                           // broadcast read
                a0 = fmaf(va.x, E[4 * c + 0], a0);
                a1 = fmaf(va.y, E[4 * c + 1], a1);
                a2 = fmaf(va.z, E[4 * c + 2], a2);
                a3 = fmaf(va.w, E[4 * c + 3], a3);
            }
            float raw = (a0 + a1) + (a2 + a3);   // strictly positive
            if ((s & 7) == 0) {                  // periodic renormalization
                float r = bcastf(raw, 0);
                raw *= __builtin_amdgcn_rcpf(r);
                M += __logf(r);
            }
            float a = raw * xe;
            abuf[(s + 1) & 1][j] = a;            // publish alpha for step s+1
            xe = __expf(nx);
            nx = (em && s + 1 < n) ? ldn : SMALL_;
        }

        // final transition-to-end: only lane L-1's value matters
        const float4* a4 = reinterpret_cast<const float4*>(abuf[(n + 1) & 1]);
        float a0 = 0.f, a1 = 0.f, a2 = 0.f, a3 = 0.f;
        #pragma unroll
        for (int c = 0; c < 12; ++c) {
            float4 va = a4[c];
            a0 = fmaf(va.x, E[4 * c + 0], a0);
            a1 = fmaf(va.y, E[4 * c + 1], a1);
            a2 = fmaf(va.z, E[4 * c + 2], a2);
            a3 = fmaf(va.w, E[4 * c + 3], a3);
        }
        float raw_end = (a0 + a1) + (a2 + a3);
        float vz = bcastf(raw_end, L_ - 1);
        logz = __logf(vz) + M;
    }
    __syncthreads();

    if (wv == 0) {
        if (j == 0) res[b] = logz - s_sc;
        // fused deterministic reduce: last block sums all 128 in fixed order
        __threadfence();
        unsigned old = 0;
        if (j == 0) old = atomicAdd(cnt, 1u);
        old = __builtin_amdgcn_readlane(old, 0);
        if (old == B_ - 1) {
            __threadfence();
            volatile const float* vr = res;
            float v2 = vr[j] + vr[64 + j];
            #pragma unroll
            for (int o = 32; o > 0; o >>= 1) v2 += __shfl_xor(v2, o, 64);
            if (j == 0) out[0] = v2;
        }
    }
}

extern "C" void kernel_launch(void* const* d_in, const int* in_sizes, int n_in,
                              void* d_out, int out_size, void* d_ws, size_t ws_size,
                              hipStream_t stream) {
    const float* x      = (const float*)d_in[0];
    const float* W      = (const float*)d_in[1];
    const float* bias   = (const float*)d_in[2];
    const float* trans  = (const float*)d_in[3];
    const int*   tags   = (const int*)d_in[4];
    const int*   seqlen = (const int*)d_in[5];
    float* out = (float*)d_out;

    float* pred = (float*)d_ws;                                      // 6291456 B
    unsigned short* wbf = (unsigned short*)((char*)d_ws + 6291456);  // 98304 B
    float* res = (float*)((char*)d_ws + 6389760);                    // 512 B
    unsigned* cnt = (unsigned*)((char*)d_ws + 6390272);              // 4 B

    hipLaunchKernelGGL(wconv_kernel, dim3(192), dim3(256), 0, stream, W, wbf, cnt);
    hipLaunchKernelGGL(gemm_kernel, dim3(1024), dim3(256), 0, stream, x, wbf, bias, pred);
    hipLaunchKernelGGL(crf_kernel, dim3(B_), dim3(256), 0, stream, pred, trans, tags, seqlen, res, cnt, out);
}

// Round 7
// 78.516 us; speedup vs baseline: 1.8403x; 1.5543x over previous
//
#include <hip/hip_runtime.h>
#include <hip/hip_bf16.h>

#define B_ 128
#define T_ 256
#define D_ 1024
#define L_ 48
#define SMALL_ (-1000.0f)

typedef float f32x4 __attribute__((ext_vector_type(4)));
typedef short bf16x8 __attribute__((ext_vector_type(8)));
typedef short bf16x4 __attribute__((ext_vector_type(4)));
typedef unsigned u32x4 __attribute__((ext_vector_type(4)));
typedef unsigned u32x2 __attribute__((ext_vector_type(2)));

__device__ __forceinline__ float bcastf(float v, int lane) {
    return __uint_as_float(__builtin_amdgcn_readlane(__float_as_uint(v), lane));
}
__device__ __forceinline__ unsigned cvt_pk_bf16(float lo, float hi) {
    unsigned r;
    asm("v_cvt_pk_bf16_f32 %0, %1, %2" : "=v"(r) : "v"(lo), "v"(hi));
    return r;
}
__device__ __forceinline__ bf16x4 pack4(float a, float b, float c, float d) {
    u32x2 u = {cvt_pk_bf16(a, b), cvt_pk_bf16(c, d)};
    return __builtin_bit_cast(bf16x4, u);
}
__device__ __forceinline__ f32x4 mfma16(bf16x4 a, bf16x4 b, f32x4 c) {
#if __has_builtin(__builtin_amdgcn_mfma_f32_16x16x16bf16_1k)
    return __builtin_amdgcn_mfma_f32_16x16x16bf16_1k(a, b, c, 0, 0, 0);
#else
    asm volatile("v_mfma_f32_16x16x16_bf16 %0, %1, %2, %0" : "+v"(c) : "v"(a), "v"(b));
    return c;
#endif
}
__device__ __forceinline__ unsigned short f2bfu(float f) {
    unsigned u = __float_as_uint(f);
    return (unsigned short)((u + 0x7FFFu + ((u >> 16) & 1u)) >> 16);
}

// ---------- Kernel 1: W -> bf16, E^T -> bf16, zero ticket ----------
__global__ __launch_bounds__(256) void prep_kernel(const float* __restrict__ W,
                                                   const float* __restrict__ trans,
                                                   unsigned short* __restrict__ wbf,
                                                   unsigned short* __restrict__ etbf,
                                                   unsigned* __restrict__ cnt) {
    int i = blockIdx.x * 256 + threadIdx.x;   // 49152 total
    if (i == 0) *cnt = 0u;
    wbf[i] = f2bfu(W[i]);
    if (i < L_ * L_) {
        int r = i / L_, k = i - r * L_;       // etbf[r][k] = exp(trans[k][r])
        etbf[i] = f2bfu(__expf(trans[k * L_ + r]));
    }
}

// ---------- Kernel 2: pred = x @ W^T + b, bf16 MFMA, 2-way K-split (R4-proven) ----------
__global__ __launch_bounds__(256, 4) void gemm_kernel(const float* __restrict__ x,
                                                      const unsigned short* __restrict__ wbf,
                                                      const float* __restrict__ bias,
                                                      float* __restrict__ pred) {
    __shared__ float red[2][64][12];
    const int wv = threadIdx.x >> 6;
    const int lane = threadIdx.x & 63;
    const int pair = wv >> 1;
    const int kh = wv & 1;
    const int m0 = blockIdx.x * 32 + pair * 16;
    const int l16 = lane & 15;
    const int lg  = lane >> 4;

    const float* xrow = x + (size_t)(m0 + l16) * D_ + kh * 512 + lg * 8;
    const unsigned short* wrow = wbf + (size_t)l16 * D_ + kh * 512 + lg * 8;
    f32x4 acc0 = {0.f,0.f,0.f,0.f}, acc1 = {0.f,0.f,0.f,0.f}, acc2 = {0.f,0.f,0.f,0.f};

    #pragma unroll 8
    for (int k0 = 0; k0 < 512; k0 += 32) {
        float4 xa = *reinterpret_cast<const float4*>(xrow + k0);
        float4 xb = *reinterpret_cast<const float4*>(xrow + k0 + 4);
        u32x4 au;
        au[0] = cvt_pk_bf16(xa.x, xa.y);
        au[1] = cvt_pk_bf16(xa.z, xa.w);
        au[2] = cvt_pk_bf16(xb.x, xb.y);
        au[3] = cvt_pk_bf16(xb.z, xb.w);
        bf16x8 af = __builtin_bit_cast(bf16x8, au);
        const unsigned short* wp = wrow + k0;
        bf16x8 b0 = *reinterpret_cast<const bf16x8*>(wp);
        bf16x8 b1 = *reinterpret_cast<const bf16x8*>(wp + 16 * D_);
        bf16x8 b2 = *reinterpret_cast<const bf16x8*>(wp + 32 * D_);
        acc0 = __builtin_amdgcn_mfma_f32_16x16x32_bf16(af, b0, acc0, 0, 0, 0);
        acc1 = __builtin_amdgcn_mfma_f32_16x16x32_bf16(af, b1, acc1, 0, 0, 0);
        acc2 = __builtin_amdgcn_mfma_f32_16x16x32_bf16(af, b2, acc2, 0, 0, 0);
    }

    if (kh == 1) {
        #pragma unroll
        for (int r = 0; r < 4; ++r) {
            red[pair][lane][r]     = acc0[r];
            red[pair][lane][4 + r] = acc1[r];
            red[pair][lane][8 + r] = acc2[r];
        }
    }
    __syncthreads();
    if (kh == 0) {
        const int rbase = m0 + lg * 4;
        float bi0 = bias[l16], bi1 = bias[16 + l16], bi2 = bias[32 + l16];
        #pragma unroll
        for (int r = 0; r < 4; ++r) {
            size_t ro = (size_t)(rbase + r) * L_;
            pred[ro + l16]      = acc0[r] + red[pair][lane][r]     + bi0;
            pred[ro + 16 + l16] = acc1[r] + red[pair][lane][4 + r] + bi1;
            pred[ro + 32 + l16] = acc2[r] + red[pair][lane][8 + r] + bi2;
        }
    }
}

// ---------- Kernel 3: chunk products X = (M_{t1}...M_{t2})^T via MFMA ----------
// One wave per chain (batch, chunk of 32 steps). X <- diag(w_t) * (E^T * X).
__global__ __launch_bounds__(256) void chunk_kernel(const float* __restrict__ pred,
                                                    const unsigned short* __restrict__ etbf,
                                                    const int* __restrict__ seq_len,
                                                    float* __restrict__ Xout,
                                                    float* __restrict__ lsc) {
    const int wv = threadIdx.x >> 6;
    const int lane = threadIdx.x & 63;
    const int chain = blockIdx.x * 4 + wv;     // 0..1023
    const int b = chain >> 3, c = chain & 7;
    const int n = seq_len[b];
    int nsteps = n - c * 32;
    nsteps = nsteps < 0 ? 0 : (nsteps > 32 ? 32 : nsteps);

    __shared__ float wlds_all[4][32 * L_];     // 24 KB, per-wave private
    float* wlds = wlds_all[wv];

    // stage w = exp(pred[chunk]) to LDS; zero cols 46,47 (masked tags)
    {
        const float4* psrc = reinterpret_cast<const float4*>(pred + ((size_t)b * T_ + c * 32) * L_);
        #pragma unroll
        for (int k = 0; k < 6; ++k) {
            int f = lane + 64 * k;             // float4 idx 0..383
            float4 v = psrc[f];
            v.x = __expf(v.x); v.y = __expf(v.y); v.z = __expf(v.z); v.w = __expf(v.w);
            if (f % 12 == 11) { v.z = 0.f; v.w = 0.f; }   // cols 46,47
            reinterpret_cast<float4*>(wlds)[f] = v;
        }
    }

    const int l15 = lane & 15, g = lane >> 4;
    // A fragments: E^T[row][k], lane holds row=l15(+16mt), k=4g+q(+16kt)
    bf16x4 A[3][3];
    #pragma unroll
    for (int mt = 0; mt < 3; ++mt)
        #pragma unroll
        for (int kt = 0; kt < 3; ++kt)
            A[mt][kt] = *reinterpret_cast<const bf16x4*>(etbf + (16 * mt + l15) * L_ + 16 * kt + 4 * g);

    // P (f32, C-fragment form): P[rt][nt][r] = X[16rt+4g+r][16nt+l15]; init identity
    float P[3][3][4];
    #pragma unroll
    for (int rt = 0; rt < 3; ++rt)
        #pragma unroll
        for (int nt = 0; nt < 3; ++nt)
            #pragma unroll
            for (int r = 0; r < 4; ++r)
                P[rt][nt][r] = (rt == nt && 4 * g + r == l15) ? 1.f : 0.f;

    float lsum = 0.f;
    for (int q = 0; q < nsteps; ++q) {
        // P (C-layout) -> bf16 B-fragments: identical lane->element mapping (K=16 trick)
        bf16x4 Bf[3][3];
        #pragma unroll
        for (int kt = 0; kt < 3; ++kt)
            #pragma unroll
            for (int nt = 0; nt < 3; ++nt)
                Bf[kt][nt] = pack4(P[kt][nt][0], P[kt][nt][1], P[kt][nt][2], P[kt][nt][3]);

        f32x4 C[3][3];
        #pragma unroll
        for (int mt = 0; mt < 3; ++mt)
            #pragma unroll
            for (int nt = 0; nt < 3; ++nt)
                C[mt][nt] = f32x4{0.f, 0.f, 0.f, 0.f};
        #pragma unroll
        for (int kt = 0; kt < 3; ++kt)
            #pragma unroll
            for (int mt = 0; mt < 3; ++mt)
                #pragma unroll
                for (int nt = 0; nt < 3; ++nt)
                    C[mt][nt] = mfma16(A[mt][kt], Bf[kt][nt], C[mt][nt]);

        // emission weights for rows 4g..4g+3 (+16mt)
        float4 w0 = *reinterpret_cast<const float4*>(wlds + q * L_ + 4 * g);
        float4 w1 = *reinterpret_cast<const float4*>(wlds + q * L_ + 16 + 4 * g);
        float4 w2 = *reinterpret_cast<const float4*>(wlds + q * L_ + 32 + 4 * g);

        float rn = 1.f;
        if ((q & 3) == 3) {                    // periodic renorm by C[0][0] (>0)
            float r = bcastf(C[0][0][0], 0);
            rn = __builtin_amdgcn_rcpf(r);
            lsum += __logf(r);
        }
        float sr[12];
        sr[0] = w0.x * rn; sr[1] = w0.y * rn; sr[2]  = w0.z * rn; sr[3]  = w0.w * rn;
        sr[4] = w1.x * rn; sr[5] = w1.y * rn; sr[6]  = w1.z * rn; sr[7]  = w1.w * rn;
        sr[8] = w2.x * rn; sr[9] = w2.y * rn; sr[10] = w2.z * rn; sr[11] = w2.w * rn;
        #pragma unroll
        for (int mt = 0; mt < 3; ++mt)
            #pragma unroll
            for (int nt = 0; nt < 3; ++nt)
                #pragma unroll
                for (int r = 0; r < 4; ++r)
                    P[mt][nt][r] = C[mt][nt][r] * sr[4 * mt + r];
    }

    // store X (f32) and log-scale
    float* xo = Xout + (size_t)chain * 2304;
    #pragma unroll
    for (int mt = 0; mt < 3; ++mt)
        #pragma unroll
        for (int nt = 0; nt < 3; ++nt)
            #pragma unroll
            for (int r = 0; r < 4; ++r)
                xo[(16 * mt + 4 * g + r) * L_ + 16 * nt + l15] = P[mt][nt][r];
    if (lane == 0) lsc[chain] = lsum;
}

// ---------- Kernel 4: per-batch combine (8 matvecs) + gold score + ticket reduce ----------
__global__ __launch_bounds__(64) void combine_kernel(const float* __restrict__ Xout,
                                                     const float* __restrict__ lsc,
                                                     const float* __restrict__ pred,
                                                     const float* __restrict__ trans,
                                                     const int* __restrict__ tags,
                                                     const int* __restrict__ seq_len,
                                                     float* __restrict__ res,
                                                     unsigned* __restrict__ cnt,
                                                     float* __restrict__ out) {
    const int b = blockIdx.x;
    const int j = threadIdx.x;
    const int n = seq_len[b];

    // gold-path score
    const int* tg = tags + b * T_;
    const float* pb = pred + (size_t)b * T_ * L_;
    float sc = 0.f;
    for (int t = j; t < n; t += 64) {
        int tag = tg[t];
        int pt = (t == 0) ? (L_ - 2) : tg[t - 1];
        sc += pb[t * L_ + tag] + trans[pt * L_ + tag];
    }
    if (j == 0) sc += trans[tg[n - 1] * L_ + (L_ - 1)];
    #pragma unroll
    for (int o = 32; o > 0; o >>= 1) sc += __shfl_xor(sc, o, 64);

    // v = e_{L-2}; v <- X_c * v per chunk (v_new[j] = sum_i X[j][i] v[i])
    __shared__ float vbuf[64];
    float v = (j == L_ - 2) ? 1.f : 0.f;
    vbuf[j] = v;
    float lsum = 0.f;
    #pragma unroll 1
    for (int c = 0; c < 8; ++c) {
        const float* X = Xout + (size_t)(b * 8 + c) * 2304;
        lsum += lsc[b * 8 + c];
        float acc = 0.f;
        if (j < L_) {
            const float4* vb4 = reinterpret_cast<const float4*>(vbuf);
            const float4* xr = reinterpret_cast<const float4*>(X + j * L_);
            #pragma unroll
            for (int ci = 0; ci < 12; ++ci) {
                float4 xx = xr[ci];
                float4 vv = vb4[ci];
                acc = fmaf(xx.x, vv.x, acc);
                acc = fmaf(xx.y, vv.y, acc);
                acc = fmaf(xx.z, vv.z, acc);
                acc = fmaf(xx.w, vv.w, acc);
            }
        }
        float r = bcastf(acc, 0);              // v_new[0] > 0 always
        float rn = __builtin_amdgcn_rcpf(r);
        lsum += __logf(r);
        v = acc * rn;
        vbuf[j] = (j < L_) ? v : 0.f;
    }

    // end transition: logZ = log(sum_j v[j]*E[j][L-1]) + lsum
    float term = (j < L_) ? v * __expf(trans[j * L_ + (L_ - 1)]) : 0.f;
    #pragma unroll
    for (int o = 32; o > 0; o >>= 1) term += __shfl_xor(term, o, 64);
    float logz = __logf(term) + lsum;

    if (j == 0) res[b] = logz - sc;
    __threadfence();
    unsigned old = 0;
    if (j == 0) old = atomicAdd(cnt, 1u);
    old = __builtin_amdgcn_readlane(old, 0);
    if (old == B_ - 1) {
        __threadfence();
        volatile const float* vr = res;
        float v2 = vr[j] + vr[64 + j];
        #pragma unroll
        for (int o = 32; o > 0; o >>= 1) v2 += __shfl_xor(v2, o, 64);
        if (j == 0) out[0] = v2;
    }
}

extern "C" void kernel_launch(void* const* d_in, const int* in_sizes, int n_in,
                              void* d_out, int out_size, void* d_ws, size_t ws_size,
                              hipStream_t stream) {
    const float* x      = (const float*)d_in[0];
    const float* W      = (const float*)d_in[1];
    const float* bias   = (const float*)d_in[2];
    const float* trans  = (const float*)d_in[3];
    const int*   tags   = (const int*)d_in[4];
    const int*   seqlen = (const int*)d_in[5];
    float* out = (float*)d_out;

    float* pred          = (float*)d_ws;                                   // 6291456 B
    unsigned short* wbf  = (unsigned short*)((char*)d_ws + 6291456);       // 98304 B
    unsigned short* etbf = (unsigned short*)((char*)d_ws + 6389760);       // 4608 B
    float* Xout          = (float*)((char*)d_ws + 6394368);                // 9437184 B
    float* lsc           = (float*)((char*)d_ws + 15831552);               // 4096 B
    float* res           = (float*)((char*)d_ws + 15835648);               // 512 B
    unsigned* cnt        = (unsigned*)((char*)d_ws + 15836160);            // 4 B

    hipLaunchKernelGGL(prep_kernel, dim3(192), dim3(256), 0, stream, W, trans, wbf, etbf, cnt);
    hipLaunchKernelGGL(gemm_kernel, dim3(1024), dim3(256), 0, stream, x, wbf, bias, pred);
    hipLaunchKernelGGL(chunk_kernel, dim3(256), dim3(256), 0, stream, pred, etbf, seqlen, Xout, lsc);
    hipLaunchKernelGGL(combine_kernel, dim3(B_), dim3(64), 0, stream,
                       Xout, lsc, pred, trans, tags, seqlen, res, cnt, out);
}

// Round 8
// 72.704 us; speedup vs baseline: 1.9874x; 1.0799x over previous
//
#include <hip/hip_runtime.h>
#include <hip/hip_bf16.h>

#define B_ 128
#define T_ 256
#define D_ 1024
#define L_ 48
#define SMALL_ (-1000.0f)

typedef float f32x4 __attribute__((ext_vector_type(4)));
typedef short bf16x8 __attribute__((ext_vector_type(8)));
typedef short bf16x4 __attribute__((ext_vector_type(4)));
typedef unsigned u32x4 __attribute__((ext_vector_type(4)));
typedef unsigned u32x2 __attribute__((ext_vector_type(2)));

__device__ __forceinline__ float bcastf(float v, int lane) {
    return __uint_as_float(__builtin_amdgcn_readlane(__float_as_uint(v), lane));
}
__device__ __forceinline__ unsigned cvt_pk_bf16(float lo, float hi) {
    unsigned r;
    asm("v_cvt_pk_bf16_f32 %0, %1, %2" : "=v"(r) : "v"(lo), "v"(hi));
    return r;
}
__device__ __forceinline__ bf16x4 pack4(float a, float b, float c, float d) {
    u32x2 u = {cvt_pk_bf16(a, b), cvt_pk_bf16(c, d)};
    return __builtin_bit_cast(bf16x4, u);
}
__device__ __forceinline__ f32x4 mfma16(bf16x4 a, bf16x4 b, f32x4 c) {
#if __has_builtin(__builtin_amdgcn_mfma_f32_16x16x16bf16_1k)
    return __builtin_amdgcn_mfma_f32_16x16x16bf16_1k(a, b, c, 0, 0, 0);
#else
    asm volatile("v_mfma_f32_16x16x16_bf16 %0, %1, %2, %0" : "+v"(c) : "v"(a), "v"(b));
    return c;
#endif
}
__device__ __forceinline__ unsigned short f2bfu(float f) {
    unsigned u = __float_as_uint(f);
    return (unsigned short)((u + 0x7FFFu + ((u >> 16) & 1u)) >> 16);
}

// ---------- Kernel 1: W -> bf16, E^T -> bf16, zero ticket ----------
__global__ __launch_bounds__(256) void prep_kernel(const float* __restrict__ W,
                                                   const float* __restrict__ trans,
                                                   unsigned short* __restrict__ wbf,
                                                   unsigned short* __restrict__ etbf,
                                                   unsigned* __restrict__ cnt) {
    int i = blockIdx.x * 256 + threadIdx.x;   // 49152 total
    if (i == 0) *cnt = 0u;
    wbf[i] = f2bfu(W[i]);
    if (i < L_ * L_) {
        int r = i / L_, k = i - r * L_;       // etbf[r][k] = exp(trans[k][r])
        etbf[i] = f2bfu(__expf(trans[k * L_ + r]));
    }
}

// ---------- Kernel 2: fused GEMM (32 rows = one chunk) + chunk matrix product ----------
// Block i = (b = i>>3, c = i&7) -> rows b*256 + c*32 (= i*32).
// Waves: (pair = wv>>1) picks 16-row half, (kh = wv&1) picks K half.
// After epilogue, wave 0 computes X = (M_{c*32+1} ... )^T via 16x16x16 MFMA.
__global__ __launch_bounds__(256, 4) void gemmchunk_kernel(const float* __restrict__ x,
                                                           const unsigned short* __restrict__ wbf,
                                                           const float* __restrict__ bias,
                                                           const unsigned short* __restrict__ etbf,
                                                           const int* __restrict__ seq_len,
                                                           float* __restrict__ pred,
                                                           float* __restrict__ Xout,
                                                           float* __restrict__ lsc) {
    __shared__ float red[2][64][12];   // 6 KB: K-split reduction
    __shared__ float elds[32 * L_];    // 6 KB: exp(pred) tile for the chunk product
    const int wv = threadIdx.x >> 6;
    const int lane = threadIdx.x & 63;
    const int pair = wv >> 1;
    const int kh = wv & 1;
    const int m0 = blockIdx.x * 32 + pair * 16;
    const int l16 = lane & 15;
    const int lg  = lane >> 4;

    // ---- GEMM phase (R4-proven) ----
    {
        const float* xrow = x + (size_t)(m0 + l16) * D_ + kh * 512 + lg * 8;
        const unsigned short* wrow = wbf + (size_t)l16 * D_ + kh * 512 + lg * 8;
        f32x4 acc0 = {0.f,0.f,0.f,0.f}, acc1 = {0.f,0.f,0.f,0.f}, acc2 = {0.f,0.f,0.f,0.f};

        #pragma unroll 8
        for (int k0 = 0; k0 < 512; k0 += 32) {
            float4 xa = *reinterpret_cast<const float4*>(xrow + k0);
            float4 xb = *reinterpret_cast<const float4*>(xrow + k0 + 4);
            u32x4 au;
            au[0] = cvt_pk_bf16(xa.x, xa.y);
            au[1] = cvt_pk_bf16(xa.z, xa.w);
            au[2] = cvt_pk_bf16(xb.x, xb.y);
            au[3] = cvt_pk_bf16(xb.z, xb.w);
            bf16x8 af = __builtin_bit_cast(bf16x8, au);
            const unsigned short* wp = wrow + k0;
            bf16x8 b0 = *reinterpret_cast<const bf16x8*>(wp);
            bf16x8 b1 = *reinterpret_cast<const bf16x8*>(wp + 16 * D_);
            bf16x8 b2 = *reinterpret_cast<const bf16x8*>(wp + 32 * D_);
            acc0 = __builtin_amdgcn_mfma_f32_16x16x32_bf16(af, b0, acc0, 0, 0, 0);
            acc1 = __builtin_amdgcn_mfma_f32_16x16x32_bf16(af, b1, acc1, 0, 0, 0);
            acc2 = __builtin_amdgcn_mfma_f32_16x16x32_bf16(af, b2, acc2, 0, 0, 0);
        }

        if (kh == 1) {
            #pragma unroll
            for (int r = 0; r < 4; ++r) {
                red[pair][lane][r]     = acc0[r];
                red[pair][lane][4 + r] = acc1[r];
                red[pair][lane][8 + r] = acc2[r];
            }
        }
        __syncthreads();
        if (kh == 0) {
            const int rbase = m0 + lg * 4;
            float bi0 = bias[l16], bi1 = bias[16 + l16], bi2 = bias[32 + l16];
            #pragma unroll
            for (int r = 0; r < 4; ++r) {
                size_t ro = (size_t)(rbase + r) * L_;
                float v0 = acc0[r] + red[pair][lane][r]     + bi0;
                float v1 = acc1[r] + red[pair][lane][4 + r] + bi1;
                float v2 = acc2[r] + red[pair][lane][8 + r] + bi2;
                pred[ro + l16]      = v0;
                pred[ro + 16 + l16] = v1;
                pred[ro + 32 + l16] = v2;
                // exp(pred) into LDS for chunk product; zero masked cols 46,47
                int lrow = pair * 16 + lg * 4 + r;
                elds[lrow * L_ + l16]      = __expf(v0);
                elds[lrow * L_ + 16 + l16] = __expf(v1);
                elds[lrow * L_ + 32 + l16] = (32 + l16 >= L_ - 2) ? 0.f : __expf(v2);
            }
        }
    }
    __syncthreads();
    if (wv != 0) return;

    // ---- chunk product phase (wave 0 only, no barriers below) ----
    const int b = blockIdx.x >> 3, c = blockIdx.x & 7;
    const int n = seq_len[b];
    int nsteps = n - c * 32;
    nsteps = nsteps < 0 ? 0 : (nsteps > 32 ? 32 : nsteps);

    const int l15 = lane & 15, g = lane >> 4;
    // A fragments: E^T[row][k], lane holds row=l15(+16mt), k=4g+q(+16kt)
    bf16x4 A[3][3];
    #pragma unroll
    for (int mt = 0; mt < 3; ++mt)
        #pragma unroll
        for (int kt = 0; kt < 3; ++kt)
            A[mt][kt] = *reinterpret_cast<const bf16x4*>(etbf + (16 * mt + l15) * L_ + 16 * kt + 4 * g);

    // Persistent state in C-fragment layout: Cst[mt][nt][r] = X[16mt+4g+r][16nt+l15]; init identity
    f32x4 Cst[3][3];
    #pragma unroll
    for (int mt = 0; mt < 3; ++mt)
        #pragma unroll
        for (int nt = 0; nt < 3; ++nt)
            #pragma unroll
            for (int r = 0; r < 4; ++r)
                Cst[mt][nt][r] = (mt == nt && 4 * g + r == l15) ? 1.f : 0.f;

    float lsum = 0.f;
    for (int q = 0; q < nsteps; ++q) {
        // state -> bf16 B-fragments (C layout == B layout for K=16)
        bf16x4 Bf[3][3];
        #pragma unroll
        for (int kt = 0; kt < 3; ++kt)
            #pragma unroll
            for (int nt = 0; nt < 3; ++nt)
                Bf[kt][nt] = pack4(Cst[kt][nt][0], Cst[kt][nt][1], Cst[kt][nt][2], Cst[kt][nt][3]);

        f32x4 C[3][3];
        #pragma unroll
        for (int mt = 0; mt < 3; ++mt)
            #pragma unroll
            for (int nt = 0; nt < 3; ++nt)
                C[mt][nt] = f32x4{0.f, 0.f, 0.f, 0.f};
        #pragma unroll
        for (int kt = 0; kt < 3; ++kt)
            #pragma unroll
            for (int mt = 0; mt < 3; ++mt)
                #pragma unroll
                for (int nt = 0; nt < 3; ++nt)
                    C[mt][nt] = mfma16(A[mt][kt], Bf[kt][nt], C[mt][nt]);

        // emission weights for rows 16*mt + 4g..4g+3
        float4 w0 = *reinterpret_cast<const float4*>(elds + q * L_ + 4 * g);
        float4 w1 = *reinterpret_cast<const float4*>(elds + q * L_ + 16 + 4 * g);
        float4 w2 = *reinterpret_cast<const float4*>(elds + q * L_ + 32 + 4 * g);

        float rn = 1.f;
        if ((q & 3) == 3) {                    // periodic renorm by C[0][0][0] (>0)
            float r = bcastf(C[0][0][0], 0);
            rn = __builtin_amdgcn_rcpf(r);
            lsum += __logf(r);
        }
        float sr[12];
        sr[0] = w0.x * rn; sr[1] = w0.y * rn; sr[2]  = w0.z * rn; sr[3]  = w0.w * rn;
        sr[4] = w1.x * rn; sr[5] = w1.y * rn; sr[6]  = w1.z * rn; sr[7]  = w1.w * rn;
        sr[8] = w2.x * rn; sr[9] = w2.y * rn; sr[10] = w2.z * rn; sr[11] = w2.w * rn;
        #pragma unroll
        for (int mt = 0; mt < 3; ++mt)
            #pragma unroll
            for (int nt = 0; nt < 3; ++nt)
                #pragma unroll
                for (int r = 0; r < 4; ++r)
                    Cst[mt][nt][r] = C[mt][nt][r] * sr[4 * mt + r];
    }

    // store X (f32) and log-scale
    float* xo = Xout + (size_t)blockIdx.x * 2304;
    #pragma unroll
    for (int mt = 0; mt < 3; ++mt)
        #pragma unroll
        for (int nt = 0; nt < 3; ++nt)
            #pragma unroll
            for (int r = 0; r < 4; ++r)
                xo[(16 * mt + 4 * g + r) * L_ + 16 * nt + l15] = Cst[mt][nt][r];
    if (lane == 0) lsc[blockIdx.x] = lsum;
}

// ---------- Kernel 3: per-batch combine (8 matvecs) + gold score + ticket reduce ----------
__global__ __launch_bounds__(64) void combine_kernel(const float* __restrict__ Xout,
                                                     const float* __restrict__ lsc,
                                                     const float* __restrict__ pred,
                                                     const float* __restrict__ trans,
                                                     const int* __restrict__ tags,
                                                     const int* __restrict__ seq_len,
                                                     float* __restrict__ res,
                                                     unsigned* __restrict__ cnt,
                                                     float* __restrict__ out) {
    const int b = blockIdx.x;
    const int j = threadIdx.x;
    const int n = seq_len[b];

    // gold-path score
    const int* tg = tags + b * T_;
    const float* pb = pred + (size_t)b * T_ * L_;
    float sc = 0.f;
    for (int t = j; t < n; t += 64) {
        int tag = tg[t];
        int pt = (t == 0) ? (L_ - 2) : tg[t - 1];
        sc += pb[t * L_ + tag] + trans[pt * L_ + tag];
    }
    if (j == 0) sc += trans[tg[n - 1] * L_ + (L_ - 1)];
    #pragma unroll
    for (int o = 32; o > 0; o >>= 1) sc += __shfl_xor(sc, o, 64);

    // v = e_{L-2}; v <- X_c * v per chunk
    __shared__ float vbuf[64];
    float v = (j == L_ - 2) ? 1.f : 0.f;
    vbuf[j] = v;
    float lsum = 0.f;
    #pragma unroll 1
    for (int c = 0; c < 8; ++c) {
        const float* X = Xout + (size_t)(b * 8 + c) * 2304;
        lsum += lsc[b * 8 + c];
        float acc = 0.f;
        if (j < L_) {
            const float4* vb4 = reinterpret_cast<const float4*>(vbuf);
            const float4* xr = reinterpret_cast<const float4*>(X + j * L_);
            #pragma unroll
            for (int ci = 0; ci < 12; ++ci) {
                float4 xx = xr[ci];
                float4 vv = vb4[ci];
                acc = fmaf(xx.x, vv.x, acc);
                acc = fmaf(xx.y, vv.y, acc);
                acc = fmaf(xx.z, vv.z, acc);
                acc = fmaf(xx.w, vv.w, acc);
            }
        }
        float r = bcastf(acc, 0);              // v_new[0] > 0 always
        float rn = __builtin_amdgcn_rcpf(r);
        lsum += __logf(r);
        v = acc * rn;
        vbuf[j] = (j < L_) ? v : 0.f;
    }

    // end transition: logZ = log(sum_j v[j]*E[j][L-1]) + lsum
    float term = (j < L_) ? v * __expf(trans[j * L_ + (L_ - 1)]) : 0.f;
    #pragma unroll
    for (int o = 32; o > 0; o >>= 1) term += __shfl_xor(term, o, 64);
    float logz = __logf(term) + lsum;

    if (j == 0) res[b] = logz - sc;
    __threadfence();
    unsigned old = 0;
    if (j == 0) old = atomicAdd(cnt, 1u);
    old = __builtin_amdgcn_readlane(old, 0);
    if (old == B_ - 1) {
        __threadfence();
        volatile const float* vr = res;
        float v2 = vr[j] + vr[64 + j];
        #pragma unroll
        for (int o = 32; o > 0; o >>= 1) v2 += __shfl_xor(v2, o, 64);
        if (j == 0) out[0] = v2;
    }
}

extern "C" void kernel_launch(void* const* d_in, const int* in_sizes, int n_in,
                              void* d_out, int out_size, void* d_ws, size_t ws_size,
                              hipStream_t stream) {
    const float* x      = (const float*)d_in[0];
    const float* W      = (const float*)d_in[1];
    const float* bias   = (const float*)d_in[2];
    const float* trans  = (const float*)d_in[3];
    const int*   tags   = (const int*)d_in[4];
    const int*   seqlen = (const int*)d_in[5];
    float* out = (float*)d_out;

    float* pred          = (float*)d_ws;                                   // 6291456 B
    unsigned short* wbf  = (unsigned short*)((char*)d_ws + 6291456);       // 98304 B
    unsigned short* etbf = (unsigned short*)((char*)d_ws + 6389760);       // 4608 B
    float* Xout          = (float*)((char*)d_ws + 6394368);                // 9437184 B
    float* lsc           = (float*)((char*)d_ws + 15831552);               // 4096 B
    float* res           = (float*)((char*)d_ws + 15835648);               // 512 B
    unsigned* cnt        = (unsigned*)((char*)d_ws + 15836160);            // 4 B

    hipLaunchKernelGGL(prep_kernel, dim3(192), dim3(256), 0, stream, W, trans, wbf, etbf, cnt);
    hipLaunchKernelGGL(gemmchunk_kernel, dim3(1024), dim3(256), 0, stream,
                       x, wbf, bias, etbf, seqlen, pred, Xout, lsc);
    hipLaunchKernelGGL(combine_kernel, dim3(B_), dim3(64), 0, stream,
                       Xout, lsc, pred, trans, tags, seqlen, res, cnt, out);
}